// Round 3
// baseline (377.853 us; speedup 1.0000x reference)
//
#include <hip/hip_runtime.h>

// Problem constants (fixed by setup_inputs: T=8, N=2048, D=256)
#define T_ALL 8
#define T1    7
#define NPTS  2048
#define DD    256
#define BM    128           // src rows per block
#define BN    128           // dst cols per LDS tile
#define BK    16            // k-tile
#define SPLIT 8             // column split factor
#define CPS   (NPTS / SPLIT)         // 256 cols per block
#define NCH   (CPS / BN)             // 2 col-chunks per block
#define NKC   (DD / BK)              // 16 k-rounds per chunk
#define NROUND (NCH * NKC)           // 32 rounds

// ws layout (floats)
#define NDF   (T_ALL * NPTS * DD)    // 4194304
#define NPART (T1 * SPLIT * NPTS)    // 114688

__device__ __forceinline__ int swzidx(int col) {
    // element col -> stored float offset within a k-row of 128:
    // slot = (col>>2) ^ ((col>>2)>>3), keep low 2 bits. Bijective; uniform
    // <=2-way banks for all read/write patterns used below.
    int s = col >> 2;
    return (((s ^ (s >> 3)) & 31) << 2) | (col & 3);
}

// ---------------------------------------------------------------------------
// Kernel 1: normalize descriptors row-wise: x / max(||x||, 1e-8)
// ---------------------------------------------------------------------------
__global__ __launch_bounds__(256) void norm_kernel(const float* __restrict__ desc,
                                                   float* __restrict__ out) {
    int gid  = blockIdx.x * blockDim.x + threadIdx.x;
    int row  = gid >> 6;
    int lane = gid & 63;

    const float4 v = reinterpret_cast<const float4*>(desc)[(size_t)row * (DD / 4) + lane];
    float s = v.x * v.x + v.y * v.y + v.z * v.z + v.w * v.w;
#pragma unroll
    for (int off = 32; off >= 1; off >>= 1)
        s += __shfl_xor(s, off, 64);
    float n = fmaxf(sqrtf(s), 1e-8f);
    float4 o = make_float4(v.x / n, v.y / n, v.z / n, v.w / n);
    reinterpret_cast<float4*>(out)[(size_t)row * (DD / 4) + lane] = o;
}

// ---------------------------------------------------------------------------
// Kernel 2: fused partial GEMM (128x256 per block) + row max/argmax.
// 256 threads = 16x16, 8x8 micro-tile, k-major swizzled LDS tiles,
// register prefetch of next round's tiles.
// ---------------------------------------------------------------------------
__global__ __launch_bounds__(256, 3) void match_kernel(const float* __restrict__ nd,
                                                       float* __restrict__ partV,
                                                       int* __restrict__ partI) {
    __shared__ __align__(16) char smem[BM * 17 * 8];   // 17408 B
    float* sA   = (float*)smem;                        // [BK][BM] k-major
    float* sB   = sA + BK * BM;                        // [BK][BN] k-major
    float* redV = (float*)smem;                        // [BM][17] (alias, epilogue only)
    int*   redI = (int*)(smem + BM * 17 * 4);

    const int bid = blockIdx.x;                        // ((t*16)+rb)*8 + sp
    const int sp  = bid & (SPLIT - 1);
    const int rb  = (bid >> 3) & 15;
    const int t   = bid >> 7;
    const int tid = threadIdx.x;
    const int tx  = tid & 15;          // col group: cols tx*8..tx*8+7
    const int ty  = tid >> 4;          // row group: rows ty*8..ty*8+7

    const float* Abase = nd + ((size_t)t * NPTS + (size_t)rb * BM) * DD;
    const float* Bbase = nd + ((size_t)(t + 1) * NPTS + (size_t)sp * CPS) * DD;

    // staging geometry: per thread two float4 per tile: (col = scol, scol+64, k4 = sk4)
    const int scol = tid & 63;
    const int sk4  = tid >> 6;         // wave-uniform
    const int w0   = swzidx(scol);
    const int w1   = swzidx(scol + 64);

    // compute read offsets (float index within a k-row)
    const int aoff0 = (((ty * 2)     ^ ((ty * 2) >> 3))     & 31) << 2;
    const int aoff1 = (((ty * 2 + 1) ^ ((ty * 2 + 1) >> 3)) & 31) << 2;
    const int boff0 = (((tx * 2)     ^ ((tx * 2) >> 3))     & 31) << 2;
    const int boff1 = (((tx * 2 + 1) ^ ((tx * 2 + 1) >> 3)) & 31) << 2;

    // prologue prefetch: round 0 (ch=0, kc=0)
    float4 pA0 = *reinterpret_cast<const float4*>(Abase + (size_t)scol * DD + sk4 * 4);
    float4 pA1 = *reinterpret_cast<const float4*>(Abase + (size_t)(scol + 64) * DD + sk4 * 4);
    float4 pB0 = *reinterpret_cast<const float4*>(Bbase + (size_t)scol * DD + sk4 * 4);
    float4 pB1 = *reinterpret_cast<const float4*>(Bbase + (size_t)(scol + 64) * DD + sk4 * 4);

    float acc[8][8];
    float bestV[8];
    int   bestI[8];
#pragma unroll
    for (int r = 0; r < 8; ++r) {
        bestV[r] = -3.0e38f; bestI[r] = 0;
#pragma unroll
        for (int c = 0; c < 8; ++c) acc[r][c] = 0.0f;
    }

    for (int g = 0; g < NROUND; ++g) {
        __syncthreads();               // previous round's reads done; LDS free
        // ---- write staged tiles (transpose to k-major, swizzled) ----
        {
            float* a0 = sA + (sk4 * 4) * BM;
            a0[0 * BM + w0] = pA0.x;  a0[1 * BM + w0] = pA0.y;
            a0[2 * BM + w0] = pA0.z;  a0[3 * BM + w0] = pA0.w;
            a0[0 * BM + w1] = pA1.x;  a0[1 * BM + w1] = pA1.y;
            a0[2 * BM + w1] = pA1.z;  a0[3 * BM + w1] = pA1.w;
            float* b0 = sB + (sk4 * 4) * BN;
            b0[0 * BN + w0] = pB0.x;  b0[1 * BN + w0] = pB0.y;
            b0[2 * BN + w0] = pB0.z;  b0[3 * BN + w0] = pB0.w;
            b0[0 * BN + w1] = pB1.x;  b0[1 * BN + w1] = pB1.y;
            b0[2 * BN + w1] = pB1.z;  b0[3 * BN + w1] = pB1.w;
        }
        // ---- issue next round's loads; wait lands after the compute phase ----
        if (g + 1 < NROUND) {
            const int kc2 = (g + 1) & (NKC - 1);
            const int ch2 = (g + 1) >> 4;
            const float* Ab = Abase + kc2 * BK + sk4 * 4;
            const float* Bb = Bbase + (size_t)(ch2 * BN) * DD + kc2 * BK + sk4 * 4;
            pA0 = *reinterpret_cast<const float4*>(Ab + (size_t)scol * DD);
            pA1 = *reinterpret_cast<const float4*>(Ab + (size_t)(scol + 64) * DD);
            pB0 = *reinterpret_cast<const float4*>(Bb + (size_t)scol * DD);
            pB1 = *reinterpret_cast<const float4*>(Bb + (size_t)(scol + 64) * DD);
        }
        __syncthreads();               // tiles ready

        // ---- compute: 16 kk x 64 FMA, 4 ds_read_b128 per kk ----
#pragma unroll
        for (int kk = 0; kk < BK; ++kk) {
            float4 a0 = *reinterpret_cast<const float4*>(&sA[kk * BM + aoff0]);
            float4 a1 = *reinterpret_cast<const float4*>(&sA[kk * BM + aoff1]);
            float4 b0 = *reinterpret_cast<const float4*>(&sB[kk * BN + boff0]);
            float4 b1 = *reinterpret_cast<const float4*>(&sB[kk * BN + boff1]);
            float av[8] = {a0.x, a0.y, a0.z, a0.w, a1.x, a1.y, a1.z, a1.w};
            float bv[8] = {b0.x, b0.y, b0.z, b0.w, b1.x, b1.y, b1.z, b1.w};
#pragma unroll
            for (int r = 0; r < 8; ++r)
#pragma unroll
                for (int c = 0; c < 8; ++c)
                    acc[r][c] = fmaf(av[r], bv[c], acc[r][c]);
        }

        // ---- chunk boundary: fold into running (val, idx), re-zero acc ----
        if ((g & (NKC - 1)) == NKC - 1) {
            const int colbase = sp * CPS + (g >> 4) * BN + tx * 8;
#pragma unroll
            for (int c = 0; c < 8; ++c) {
                const int col = colbase + c;     // ascending -> '>' keeps first
#pragma unroll
                for (int r = 0; r < 8; ++r) {
                    if (acc[r][c] > bestV[r]) { bestV[r] = acc[r][c]; bestI[r] = col; }
                }
            }
#pragma unroll
            for (int r = 0; r < 8; ++r)
#pragma unroll
                for (int c = 0; c < 8; ++c) acc[r][c] = 0.0f;
        }
    }

    // ---- cross-thread reduction: 16 col-group partials per row ----
    __syncthreads();                   // last compute reads done; alias LDS
#pragma unroll
    for (int r = 0; r < 8; ++r) {
        redV[(ty * 8 + r) * 17 + tx] = bestV[r];
        redI[(ty * 8 + r) * 17 + tx] = bestI[r];
    }
    __syncthreads();

    if (tid < BM) {
        float bv = redV[tid * 17];
        int   bi = redI[tid * 17];
#pragma unroll
        for (int jj = 1; jj < 16; ++jj) {
            float v  = redV[tid * 17 + jj];
            int   ix = redI[tid * 17 + jj];
            if (v > bv || (v == bv && ix < bi)) { bv = v; bi = ix; }
        }
        int idx = ((t * SPLIT + sp) << 11) + rb * BM + tid;
        partV[idx] = bv;
        partI[idx] = bi;
    }
}

// ---------------------------------------------------------------------------
// Kernel 3: merge the SPLIT partials per row, gather points, write output.
// ---------------------------------------------------------------------------
__global__ __launch_bounds__(256) void reduce_kernel(const float* __restrict__ partV,
                                                     const int* __restrict__ partI,
                                                     const float* __restrict__ pts,
                                                     float* __restrict__ out) {
    int r = blockIdx.x * 256 + threadIdx.x;     // 0 .. T1*NPTS-1
    int t   = r >> 11;
    int row = r & (NPTS - 1);

    float bv = -3.0e38f;
    int   bi = 0;
#pragma unroll
    for (int sp = 0; sp < SPLIT; ++sp) {
        int idx = ((t * SPLIT + sp) << 11) + row;
        float v  = partV[idx];
        int   ix = partI[idx];
        if (v > bv || (v == bv && ix < bi)) { bv = v; bi = ix; }
    }
    out[(size_t)T1 * NPTS * 2 + r] = bv;
    const float* p = pts + ((size_t)(t + 1) * NPTS + bi) * 2;
    out[(size_t)r * 2 + 0] = p[0];
    out[(size_t)r * 2 + 1] = p[1];
}

// ---------------------------------------------------------------------------
extern "C" void kernel_launch(void* const* d_in, const int* in_sizes, int n_in,
                              void* d_out, int out_size, void* d_ws, size_t ws_size,
                              hipStream_t stream) {
    const float* desc = (const float*)d_in[0];   // [8, 2048, 256] fp32
    const float* pts  = (const float*)d_in[1];   // [8, 2048, 2]   fp32
    float* nd    = (float*)d_ws;                 // 16 MB normalized copy
    float* partV = nd + NDF;
    int*   partI = (int*)(nd + NDF + NPART);

    norm_kernel<<<(T_ALL * NPTS) / 4, 256, 0, stream>>>(desc, nd);
    match_kernel<<<T1 * 16 * SPLIT, 256, 0, stream>>>(nd, partV, partI);
    reduce_kernel<<<(T1 * NPTS) / 256, 256, 0, stream>>>(partV, partI, pts, (float*)d_out);
}

// Round 4
// 214.640 us; speedup vs baseline: 1.7604x; 1.7604x over previous
//
#include <hip/hip_runtime.h>

// Problem constants (fixed by setup_inputs: T=8, N=2048, D=256)
#define T_ALL 8
#define T1    7
#define NPTS  2048
#define DD    256
#define BM    128           // src rows per block
#define BN    128           // dst cols per LDS tile
#define BK    16            // k-tile
#define SPLIT 8             // column split factor
#define CPS   (NPTS / SPLIT)         // 256 cols per block
#define NCH   (CPS / BN)             // 2 col-chunks per block
#define NKC   (DD / BK)              // 16 k-rounds per chunk
#define NROUND (NCH * NKC)           // 32 rounds

// ws layout (floats)
#define NDF   (T_ALL * NPTS * DD)    // 4194304
#define NPART (T1 * SPLIT * NPTS)    // 114688

__device__ __forceinline__ int swzidx(int col) {
    // element col -> stored float offset within a k-row of 128:
    // slot = (col>>2) ^ ((col>>2)>>3), keep low 2 bits. Bijective; uniform
    // <=2-way banks for all read/write patterns used below.
    int s = col >> 2;
    return (((s ^ (s >> 3)) & 31) << 2) | (col & 3);
}

// ---------------------------------------------------------------------------
// Kernel 1: normalize descriptors row-wise: x / max(||x||, 1e-8)
// ---------------------------------------------------------------------------
__global__ __launch_bounds__(256) void norm_kernel(const float* __restrict__ desc,
                                                   float* __restrict__ out) {
    int gid  = blockIdx.x * blockDim.x + threadIdx.x;
    int row  = gid >> 6;
    int lane = gid & 63;

    const float4 v = reinterpret_cast<const float4*>(desc)[(size_t)row * (DD / 4) + lane];
    float s = v.x * v.x + v.y * v.y + v.z * v.z + v.w * v.w;
#pragma unroll
    for (int off = 32; off >= 1; off >>= 1)
        s += __shfl_xor(s, off, 64);
    float n = fmaxf(sqrtf(s), 1e-8f);
    float4 o = make_float4(v.x / n, v.y / n, v.z / n, v.w / n);
    reinterpret_cast<float4*>(out)[(size_t)row * (DD / 4) + lane] = o;
}

// ---------------------------------------------------------------------------
// Kernel 2: fused partial GEMM (128x256 per block) + row max/argmax.
// 256 threads = 16x16, 8x8 micro-tile, k-major swizzled LDS tiles,
// register prefetch of next round's tiles.
// NOTE: no min-occupancy in __launch_bounds__ — a (256,3) bound clamped
// VGPRs to 84 and spilled the accumulator (589 MB scratch writes, R3).
// ---------------------------------------------------------------------------
__global__ __launch_bounds__(256) void match_kernel(const float* __restrict__ nd,
                                                    float* __restrict__ partV,
                                                    int* __restrict__ partI) {
    __shared__ __align__(16) char smem[BM * 17 * 8];   // 17408 B
    float* sA   = (float*)smem;                        // [BK][BM] k-major
    float* sB   = sA + BK * BM;                        // [BK][BN] k-major
    float* redV = (float*)smem;                        // [BM][17] (alias, epilogue only)
    int*   redI = (int*)(smem + BM * 17 * 4);

    const int bid = blockIdx.x;                        // ((t*16)+rb)*8 + sp
    const int sp  = bid & (SPLIT - 1);
    const int rb  = (bid >> 3) & 15;
    const int t   = bid >> 7;
    const int tid = threadIdx.x;
    const int tx  = tid & 15;          // col group: cols tx*8..tx*8+7
    const int ty  = tid >> 4;          // row group: rows ty*8..ty*8+7

    const float* Abase = nd + ((size_t)t * NPTS + (size_t)rb * BM) * DD;
    const float* Bbase = nd + ((size_t)(t + 1) * NPTS + (size_t)sp * CPS) * DD;

    // staging geometry: per thread two float4 per tile: (col = scol, scol+64, k4 = sk4)
    const int scol = tid & 63;
    const int sk4  = tid >> 6;         // wave-uniform
    const int w0   = swzidx(scol);
    const int w1   = swzidx(scol + 64);

    // compute read offsets (float index within a k-row)
    const int aoff0 = (((ty * 2)     ^ ((ty * 2) >> 3))     & 31) << 2;
    const int aoff1 = (((ty * 2 + 1) ^ ((ty * 2 + 1) >> 3)) & 31) << 2;
    const int boff0 = (((tx * 2)     ^ ((tx * 2) >> 3))     & 31) << 2;
    const int boff1 = (((tx * 2 + 1) ^ ((tx * 2 + 1) >> 3)) & 31) << 2;

    // prologue prefetch: round 0 (ch=0, kc=0)
    float4 pA0 = *reinterpret_cast<const float4*>(Abase + (size_t)scol * DD + sk4 * 4);
    float4 pA1 = *reinterpret_cast<const float4*>(Abase + (size_t)(scol + 64) * DD + sk4 * 4);
    float4 pB0 = *reinterpret_cast<const float4*>(Bbase + (size_t)scol * DD + sk4 * 4);
    float4 pB1 = *reinterpret_cast<const float4*>(Bbase + (size_t)(scol + 64) * DD + sk4 * 4);

    float acc[8][8];
    float bestV[8];
    int   bestI[8];
#pragma unroll
    for (int r = 0; r < 8; ++r) {
        bestV[r] = -3.0e38f; bestI[r] = 0;
#pragma unroll
        for (int c = 0; c < 8; ++c) acc[r][c] = 0.0f;
    }

    for (int g = 0; g < NROUND; ++g) {
        __syncthreads();               // previous round's reads done; LDS free
        // ---- write staged tiles (transpose to k-major, swizzled) ----
        {
            float* a0 = sA + (sk4 * 4) * BM;
            a0[0 * BM + w0] = pA0.x;  a0[1 * BM + w0] = pA0.y;
            a0[2 * BM + w0] = pA0.z;  a0[3 * BM + w0] = pA0.w;
            a0[0 * BM + w1] = pA1.x;  a0[1 * BM + w1] = pA1.y;
            a0[2 * BM + w1] = pA1.z;  a0[3 * BM + w1] = pA1.w;
            float* b0 = sB + (sk4 * 4) * BN;
            b0[0 * BN + w0] = pB0.x;  b0[1 * BN + w0] = pB0.y;
            b0[2 * BN + w0] = pB0.z;  b0[3 * BN + w0] = pB0.w;
            b0[0 * BN + w1] = pB1.x;  b0[1 * BN + w1] = pB1.y;
            b0[2 * BN + w1] = pB1.z;  b0[3 * BN + w1] = pB1.w;
        }
        // ---- issue next round's loads; wait lands after the compute phase ----
        if (g + 1 < NROUND) {
            const int kc2 = (g + 1) & (NKC - 1);
            const int ch2 = (g + 1) >> 4;
            const float* Ab = Abase + kc2 * BK + sk4 * 4;
            const float* Bb = Bbase + (size_t)(ch2 * BN) * DD + kc2 * BK + sk4 * 4;
            pA0 = *reinterpret_cast<const float4*>(Ab + (size_t)scol * DD);
            pA1 = *reinterpret_cast<const float4*>(Ab + (size_t)(scol + 64) * DD);
            pB0 = *reinterpret_cast<const float4*>(Bb + (size_t)scol * DD);
            pB1 = *reinterpret_cast<const float4*>(Bb + (size_t)(scol + 64) * DD);
        }
        __syncthreads();               // tiles ready

        // ---- compute: 16 kk x 64 FMA, 4 ds_read_b128 per kk ----
#pragma unroll
        for (int kk = 0; kk < BK; ++kk) {
            float4 a0 = *reinterpret_cast<const float4*>(&sA[kk * BM + aoff0]);
            float4 a1 = *reinterpret_cast<const float4*>(&sA[kk * BM + aoff1]);
            float4 b0 = *reinterpret_cast<const float4*>(&sB[kk * BN + boff0]);
            float4 b1 = *reinterpret_cast<const float4*>(&sB[kk * BN + boff1]);
            float av[8] = {a0.x, a0.y, a0.z, a0.w, a1.x, a1.y, a1.z, a1.w};
            float bv[8] = {b0.x, b0.y, b0.z, b0.w, b1.x, b1.y, b1.z, b1.w};
#pragma unroll
            for (int r = 0; r < 8; ++r)
#pragma unroll
                for (int c = 0; c < 8; ++c)
                    acc[r][c] = fmaf(av[r], bv[c], acc[r][c]);
        }

        // ---- chunk boundary: fold into running (val, idx), re-zero acc ----
        if ((g & (NKC - 1)) == NKC - 1) {
            const int colbase = sp * CPS + (g >> 4) * BN + tx * 8;
#pragma unroll
            for (int c = 0; c < 8; ++c) {
                const int col = colbase + c;     // ascending -> '>' keeps first
#pragma unroll
                for (int r = 0; r < 8; ++r) {
                    if (acc[r][c] > bestV[r]) { bestV[r] = acc[r][c]; bestI[r] = col; }
                }
            }
#pragma unroll
            for (int r = 0; r < 8; ++r)
#pragma unroll
                for (int c = 0; c < 8; ++c) acc[r][c] = 0.0f;
        }
    }

    // ---- cross-thread reduction: 16 col-group partials per row ----
    __syncthreads();                   // last compute reads done; alias LDS
#pragma unroll
    for (int r = 0; r < 8; ++r) {
        redV[(ty * 8 + r) * 17 + tx] = bestV[r];
        redI[(ty * 8 + r) * 17 + tx] = bestI[r];
    }
    __syncthreads();

    if (tid < BM) {
        float bv = redV[tid * 17];
        int   bi = redI[tid * 17];
#pragma unroll
        for (int jj = 1; jj < 16; ++jj) {
            float v  = redV[tid * 17 + jj];
            int   ix = redI[tid * 17 + jj];
            if (v > bv || (v == bv && ix < bi)) { bv = v; bi = ix; }
        }
        int idx = ((t * SPLIT + sp) << 11) + rb * BM + tid;
        partV[idx] = bv;
        partI[idx] = bi;
    }
}

// ---------------------------------------------------------------------------
// Kernel 3: merge the SPLIT partials per row, gather points, write output.
// ---------------------------------------------------------------------------
__global__ __launch_bounds__(256) void reduce_kernel(const float* __restrict__ partV,
                                                     const int* __restrict__ partI,
                                                     const float* __restrict__ pts,
                                                     float* __restrict__ out) {
    int r = blockIdx.x * 256 + threadIdx.x;     // 0 .. T1*NPTS-1
    int t   = r >> 11;
    int row = r & (NPTS - 1);

    float bv = -3.0e38f;
    int   bi = 0;
#pragma unroll
    for (int sp = 0; sp < SPLIT; ++sp) {
        int idx = ((t * SPLIT + sp) << 11) + row;
        float v  = partV[idx];
        int   ix = partI[idx];
        if (v > bv || (v == bv && ix < bi)) { bv = v; bi = ix; }
    }
    out[(size_t)T1 * NPTS * 2 + r] = bv;
    const float* p = pts + ((size_t)(t + 1) * NPTS + bi) * 2;
    out[(size_t)r * 2 + 0] = p[0];
    out[(size_t)r * 2 + 1] = p[1];
}

// ---------------------------------------------------------------------------
extern "C" void kernel_launch(void* const* d_in, const int* in_sizes, int n_in,
                              void* d_out, int out_size, void* d_ws, size_t ws_size,
                              hipStream_t stream) {
    const float* desc = (const float*)d_in[0];   // [8, 2048, 256] fp32
    const float* pts  = (const float*)d_in[1];   // [8, 2048, 2]   fp32
    float* nd    = (float*)d_ws;                 // 16 MB normalized copy
    float* partV = nd + NDF;
    int*   partI = (int*)(nd + NDF + NPART);

    norm_kernel<<<(T_ALL * NPTS) / 4, 256, 0, stream>>>(desc, nd);
    match_kernel<<<T1 * 16 * SPLIT, 256, 0, stream>>>(nd, partV, partI);
    reduce_kernel<<<(T1 * NPTS) / 256, 256, 0, stream>>>(partV, partI, pts, (float*)d_out);
}